// Round 2
// baseline (1966.956 us; speedup 1.0000x reference)
//
#include <hip/hip_runtime.h>
#include <math.h>

#define NG 800000   // 800000 = 3125 * 256 exactly

__device__ __forceinline__ float sis(float t) {
    t = fminf(fmaxf(t, 0.01f), 0.99f);
    return logf(t / (1.0f - t));
}

// ---------------------------------------------------------------------------
// Prep: transpose W2 (64x128 -> 128x64) into ws, precompute b3+b_inst.
// ---------------------------------------------------------------------------
__global__ __launch_bounds__(256) void k_prep(
    const float* __restrict__ W2, const float* __restrict__ b3,
    const float* __restrict__ bi, float* __restrict__ w2t,
    float* __restrict__ bc)
{
    for (int idx = threadIdx.x; idx < 64 * 128; idx += 256) {
        int r = idx >> 7;      // 0..63
        int c = idx & 127;     // 0..127
        w2t[c * 64 + r] = W2[idx];
    }
    if (threadIdx.x < 96) bc[threadIdx.x] = b3[threadIdx.x] + bi[threadIdx.x];
}

// ---------------------------------------------------------------------------
// Kernel 1: geometry, masks, anchor, tag, pool copy, reuse mask, zero-fill of
// inactive inst rows, compaction of active indices. LDS-staged coalesced I/O.
// ---------------------------------------------------------------------------
__global__ __launch_bounds__(256) void k_geom(
    const float* __restrict__ gp,
    const float* __restrict__ w2c,
    const float* __restrict__ ck,
    const float* __restrict__ vo,
    const float* __restrict__ ss,
    const float* __restrict__ cvr,
    float* __restrict__ oA, float* __restrict__ oT,
    float* __restrict__ oI, float* __restrict__ oP,
    float* __restrict__ oM,
    int* __restrict__ cnt, int* __restrict__ lst, int compact)
{
    __shared__ float sB[256 * 25];   // gp rows in / pool rows out
    __shared__ float sA[256 * 23];   // anchor rows out

    const long base = (long)blockIdx.x * 256;
    const int t = threadIdx.x;

    // coalesced load of 256 rows (6400 floats = 1600 float4)
    {
        const float4* src = (const float4*)(gp + base * 25);
        float4* dst = (float4*)sB;
        for (int k = t; k < 1600; k += 256) dst[k] = src[k];
    }
    __syncthreads();

    float v[25];
    #pragma unroll
    for (int j = 0; j < 25; ++j) v[j] = sB[t * 25 + j];

    float R00=w2c[0],R01=w2c[1],R02=w2c[2],T0=w2c[3];
    float R10=w2c[4],R11=w2c[5],R12=w2c[6],T1=w2c[7];
    float R20=w2c[8],R21=w2c[9],R22=w2c[10],T2=w2c[11];
    float x=v[0], y=v[1], zz=v[2];
    float c0 = R00*x + R01*y + R02*zz + T0;
    float c1 = R10*x + R11*y + R12*zz + T1;
    float c2 = R20*x + R21*y + R22*zz + T2;

    bool m1 = c2 > 1e-6f;
    float zc = m1 ? c2 : 1e-6f;
    float fpx = ck[0] * c0 / zc + ck[2];
    float fpy = ck[4] * c1 / zc + ck[5];
    bool m2 = (fpx >= 0.f) && (fpx < 640.f) && (fpy >= 0.f) && (fpy < 480.f);
    bool mall = m1 && m2;

    float n0=vo[0]+1e-3f, n1=vo[1]+1e-3f, n2=vo[2]+1e-3f;
    float f0=vo[0]+ss[0]-1e-3f, f1=vo[1]+ss[1]-1e-3f, f2=vo[2]+ss[2]-1e-3f;
    bool gpm = (x>n0)&&(x<f0)&&(y>n1)&&(y<f1)&&(zz>n2)&&(zz<f2);
    bool mdet = mall && gpm;

    // patch pool col 24 in LDS
    sB[t * 25 + 24] = gpm ? 1.0f : v[24];

    float tag = (v[23] == 1.0f) ? 0.5f : 0.0f;
    if (!mdet) tag = 1.0f;

    bool gm = (c0>=cvr[0])&&(c0<=cvr[3])&&(c1>=cvr[1])&&(c1<=cvr[4])&&(c2>=cvr[2])&&(c2<=cvr[5]);
    bool reuse = gpm && gm;

    const long i = base + t;
    oM[i] = reuse ? 1.0f : 0.0f;
    oT[i] = reuse ? tag : 0.0f;

    if (reuse) {
        float tr = R00 + R11 + R22;
        float qw = sqrtf(fmaxf(tr + 1.0f, 1e-8f)) * 0.5f;
        float inv4 = 0.25f / qw;
        float qx = (R21-R12)*inv4, qy=(R02-R20)*inv4, qz=(R10-R01)*inv4;
        float p0=v[6], p1=v[7], p2=v[8], p3=v[9];
        float* ar = &sA[t * 23];
        ar[0] = sis((c0 - cvr[0]) / (cvr[3]-cvr[0]));
        ar[1] = sis((c1 - cvr[1]) / (cvr[4]-cvr[1]));
        ar[2] = sis((c2 - cvr[2]) / (cvr[5]-cvr[2]));
        ar[3] = sis(v[3]); ar[4] = sis(v[4]); ar[5] = sis(v[5]);
        ar[6] = qw*p0 - qx*p1 - qy*p2 - qz*p3;
        ar[7] = qw*p1 + qx*p0 + qy*p3 - qz*p2;
        ar[8] = qw*p2 - qx*p3 + qy*p0 + qz*p1;
        ar[9] = qw*p3 + qx*p2 - qy*p1 + qz*p0;
        ar[10] = sis(v[10]);
        #pragma unroll
        for (int j = 0; j < 12; ++j) ar[11 + j] = v[11 + j];
        if (compact) {
            int slot = atomicAdd(cnt, 1);
            lst[slot] = (int)i;
        }
    } else {
        float* ar = &sA[t * 23];
        #pragma unroll
        for (int j = 0; j < 23; ++j) ar[j] = 0.0f;
        // zero-fill inst row (scattered but line-dense)
        float4* ir = (float4*)(oI + i * 96);
        float4 z4 = make_float4(0.f, 0.f, 0.f, 0.f);
        #pragma unroll
        for (int k = 0; k < 24; ++k) ir[k] = z4;
    }
    __syncthreads();

    // coalesced stores: pool (1600 float4) and anchor (1472 float4)
    {
        const float4* s = (const float4*)sB;
        float4* d = (float4*)(oP + base * 25);
        for (int k = t; k < 1600; k += 256) d[k] = s[k];
        const float4* s2 = (const float4*)sA;
        float4* d2 = (float4*)(oA + base * 23);
        for (int k = t; k < 1472; k += 256) d2[k] = s2[k];
    }
}

// ---------------------------------------------------------------------------
// Kernel 2: depth MLP (2->64->128->96) + anchor @ W_inst.
// 4 threads per gaussian, 64 gaussians per 256-thread block.
// h2 (128) passes through LDS; W2 is pre-transposed in ws (mode==2).
// mode: 2 = compact + W2T, 1 = compact only, 0 = dense (mask check).
// ---------------------------------------------------------------------------
__global__ __launch_bounds__(256) void k_mlp(
    const float* __restrict__ gp,
    const float* __restrict__ zbuf,
    const float* __restrict__ w2c,
    const float* __restrict__ ck,
    const float* __restrict__ W1, const float* __restrict__ b1,
    const float* __restrict__ W2, const float* __restrict__ b2,
    const float* __restrict__ W3, const float* __restrict__ b3,
    const float* __restrict__ Wi, const float* __restrict__ bi,
    const float* __restrict__ anc,
    float* __restrict__ oI,
    const int* __restrict__ cnt, const int* __restrict__ lst,
    const float* __restrict__ msk,
    const float* __restrict__ w2t, const float* __restrict__ bc,
    int mode)
{
    __shared__ float sH2[64 * 133];  // padded: stride 133 -> broadcast reads

    const int n = (mode > 0) ? *cnt : NG;
    const long tbase = (long)blockIdx.x * 64;
    if (tbase >= n) return;

    const int g = threadIdx.x >> 2;    // 0..63
    const int sub = threadIdx.x & 3;   // 0..3
    const long t = tbase + g;
    bool act = (t < n);
    int i = 0;
    if (act) {
        if (mode > 0) i = lst[t];
        else { i = (int)t; act = (msk[t] != 0.0f); }
    }

    // df = [z[iy,ix], depth_real] (redundant x4, cheap)
    float d0 = 0.f, d1 = 0.f;
    if (act) {
        const float* gr = gp + (long)i * 25;
        float x = gr[0], y = gr[1], zz = gr[2];
        float c0 = w2c[0]*x + w2c[1]*y + w2c[2]*zz + w2c[3];
        float c1 = w2c[4]*x + w2c[5]*y + w2c[6]*zz + w2c[7];
        float c2 = w2c[8]*x + w2c[9]*y + w2c[10]*zz + w2c[11];
        float czs = (fabsf(c2) < 1e-6f) ? 1e-6f : c2;
        float px = ck[0]*c0/czs + ck[2];
        float py = ck[4]*c1/czs + ck[5];
        int ix = (int)fminf(fmaxf(px, 0.f), 639.f);
        int iy = (int)fminf(fmaxf(py, 0.f), 479.f);
        d0 = zbuf[iy * 640 + ix];
        d1 = c2;
    }

    // h1 = relu(df @ W1 + b1)
    float h1[64];
    #pragma unroll
    for (int j = 0; j < 64; ++j)
        h1[j] = fmaxf(d0 * W1[j] + d1 * W1[64 + j] + b1[j], 0.0f);

    // Phase A: h2[j] for j in [sub*32, sub*32+32)
    #pragma unroll 4
    for (int jj = 0; jj < 32; ++jj) {
        int j = (sub << 5) + jj;
        float s = b2[j];
        if (mode == 2) {
            const float4* wc = (const float4*)(w2t + j * 64);
            #pragma unroll
            for (int q = 0; q < 16; ++q) {
                float4 w = wc[q];
                s += h1[4*q] * w.x + h1[4*q+1] * w.y + h1[4*q+2] * w.z + h1[4*q+3] * w.w;
            }
        } else {
            #pragma unroll
            for (int q = 0; q < 64; ++q) s += h1[q] * W2[q * 128 + j];
        }
        sH2[g * 133 + j] = fmaxf(s, 0.0f);
    }
    __syncthreads();

    // Phase B: acc[24] over output cols [sub*24, sub*24+24)
    float acc[24];
    #pragma unroll
    for (int k = 0; k < 24; ++k)
        acc[k] = (mode == 2) ? bc[sub * 24 + k] : (b3[sub * 24 + k] + bi[sub * 24 + k]);

    const float* h2p = &sH2[g * 133];
    #pragma unroll 2
    for (int j = 0; j < 128; ++j) {
        float s = h2p[j];
        const float4* w3 = (const float4*)(W3 + j * 96 + sub * 24);
        #pragma unroll
        for (int q = 0; q < 6; ++q) {
            float4 w = w3[q];
            acc[4*q]   += s * w.x;
            acc[4*q+1] += s * w.y;
            acc[4*q+2] += s * w.z;
            acc[4*q+3] += s * w.w;
        }
    }

    if (act) {
        const float* ar = anc + (long)i * 23;
        #pragma unroll
        for (int c = 0; c < 23; ++c) {
            float av = ar[c];
            const float4* wi4 = (const float4*)(Wi + c * 96 + sub * 24);
            #pragma unroll
            for (int q = 0; q < 6; ++q) {
                float4 w = wi4[q];
                acc[4*q]   += av * w.x;
                acc[4*q+1] += av * w.y;
                acc[4*q+2] += av * w.z;
                acc[4*q+3] += av * w.w;
            }
        }
        float4* dst = (float4*)(oI + (long)i * 96 + sub * 24);
        #pragma unroll
        for (int q = 0; q < 6; ++q)
            dst[q] = make_float4(acc[4*q], acc[4*q+1], acc[4*q+2], acc[4*q+3]);
    }
}

extern "C" void kernel_launch(void* const* d_in, const int* in_sizes, int n_in,
                              void* d_out, int out_size, void* d_ws, size_t ws_size,
                              hipStream_t stream)
{
    const float* gp  = (const float*)d_in[0];
    const float* zb  = (const float*)d_in[2];
    const float* w2c = (const float*)d_in[3];
    const float* ck  = (const float*)d_in[4];
    const float* vo  = (const float*)d_in[5];
    const float* ss  = (const float*)d_in[6];
    const float* cvr = (const float*)d_in[7];
    const float* Wi  = (const float*)d_in[8];
    const float* bi  = (const float*)d_in[9];
    const float* W1  = (const float*)d_in[10];
    const float* b1  = (const float*)d_in[11];
    const float* W2  = (const float*)d_in[12];
    const float* b2  = (const float*)d_in[13];
    const float* W3  = (const float*)d_in[14];
    const float* b3  = (const float*)d_in[15];

    float* out = (float*)d_out;
    const long N = NG;
    float* oA = out;               // (N,23)
    float* oT = out + 23L * N;     // (N,)
    float* oI = out + 24L * N;     // (N,96)
    float* oP = out + 120L * N;    // (N,25)
    float* oM = out + 145L * N;    // (N,)

    const size_t req_lst  = 16 + 4 * (size_t)NG;
    const size_t off_w2t  = (req_lst + 255) & ~(size_t)255;
    const size_t off_bc   = off_w2t + 64 * 128 * 4;
    const size_t req_full = off_bc + 96 * 4;

    int mode;
    if (ws_size >= req_full)      mode = 2;
    else if (ws_size >= req_lst)  mode = 1;
    else                          mode = 0;

    int* cnt = (int*)d_ws;
    int* lst = (int*)d_ws + 4;
    float* w2t = (float*)((char*)d_ws + off_w2t);
    float* bcp = (float*)((char*)d_ws + off_bc);

    if (mode > 0) hipMemsetAsync(d_ws, 0, 16, stream);
    if (mode == 2) k_prep<<<1, 256, 0, stream>>>(W2, b3, bi, w2t, bcp);

    k_geom<<<NG / 256, 256, 0, stream>>>(gp, w2c, ck, vo, ss, cvr,
                                         oA, oT, oI, oP, oM, cnt, lst,
                                         mode > 0 ? 1 : 0);
    k_mlp<<<(NG + 63) / 64, 256, 0, stream>>>(gp, zb, w2c, ck, W1, b1, W2, b2,
                                              W3, b3, Wi, bi, oA, oI, cnt, lst,
                                              oM, w2t, bcp, mode);
}

// Round 3
// 251.465 us; speedup vs baseline: 7.8220x; 7.8220x over previous
//
#include <hip/hip_runtime.h>
#include <math.h>

#define NG 800000   // = 3125*256 = 12500*64

typedef __attribute__((ext_vector_type(8))) short short8;
typedef __attribute__((ext_vector_type(4))) float f32x4;

__device__ __forceinline__ float sis(float t) {
    t = fminf(fmaxf(t, 0.01f), 0.99f);
    return logf(t / (1.0f - t));
}

__device__ __forceinline__ unsigned short f2bf(float f) {
    unsigned int u = __float_as_uint(f);
    unsigned int r = (u + 0x7FFFu + ((u >> 16) & 1u)) >> 16;
    return (unsigned short)r;
}

union U8 { unsigned short u[8]; short8 v; };

// ---------------------------------------------------------------------------
// Kernel 1: geometry, masks, anchor, tag, pool copy, reuse mask.
// (no oI zero-fill anymore: k_mlp writes every row, masked)
// ---------------------------------------------------------------------------
__global__ __launch_bounds__(256) void k_geom(
    const float* __restrict__ gp,
    const float* __restrict__ w2c,
    const float* __restrict__ ck,
    const float* __restrict__ vo,
    const float* __restrict__ ss,
    const float* __restrict__ cvr,
    float* __restrict__ oA, float* __restrict__ oT,
    float* __restrict__ oP, float* __restrict__ oM)
{
    __shared__ __align__(16) float sB[256 * 25];
    __shared__ __align__(16) float sA[256 * 23];

    const long base = (long)blockIdx.x * 256;
    const int t = threadIdx.x;

    {
        const float4* src = (const float4*)(gp + base * 25);
        float4* dst = (float4*)sB;
        for (int k = t; k < 1600; k += 256) dst[k] = src[k];
    }
    __syncthreads();

    float v[25];
    #pragma unroll
    for (int j = 0; j < 25; ++j) v[j] = sB[t * 25 + j];

    float R00=w2c[0],R01=w2c[1],R02=w2c[2],T0=w2c[3];
    float R10=w2c[4],R11=w2c[5],R12=w2c[6],T1=w2c[7];
    float R20=w2c[8],R21=w2c[9],R22=w2c[10],T2=w2c[11];
    float x=v[0], y=v[1], zz=v[2];
    float c0 = R00*x + R01*y + R02*zz + T0;
    float c1 = R10*x + R11*y + R12*zz + T1;
    float c2 = R20*x + R21*y + R22*zz + T2;

    bool m1 = c2 > 1e-6f;
    float zc = m1 ? c2 : 1e-6f;
    float fpx = ck[0] * c0 / zc + ck[2];
    float fpy = ck[4] * c1 / zc + ck[5];
    bool m2 = (fpx >= 0.f) && (fpx < 640.f) && (fpy >= 0.f) && (fpy < 480.f);
    bool mall = m1 && m2;

    float n0=vo[0]+1e-3f, n1=vo[1]+1e-3f, n2=vo[2]+1e-3f;
    float f0=vo[0]+ss[0]-1e-3f, f1=vo[1]+ss[1]-1e-3f, f2=vo[2]+ss[2]-1e-3f;
    bool gpm = (x>n0)&&(x<f0)&&(y>n1)&&(y<f1)&&(zz>n2)&&(zz<f2);
    bool mdet = mall && gpm;

    sB[t * 25 + 24] = gpm ? 1.0f : v[24];

    float tag = (v[23] == 1.0f) ? 0.5f : 0.0f;
    if (!mdet) tag = 1.0f;

    bool gm = (c0>=cvr[0])&&(c0<=cvr[3])&&(c1>=cvr[1])&&(c1<=cvr[4])&&(c2>=cvr[2])&&(c2<=cvr[5]);
    bool reuse = gpm && gm;

    const long i = base + t;
    oM[i] = reuse ? 1.0f : 0.0f;
    oT[i] = reuse ? tag : 0.0f;

    float* ar = &sA[t * 23];
    if (reuse) {
        float tr = R00 + R11 + R22;
        float qw = sqrtf(fmaxf(tr + 1.0f, 1e-8f)) * 0.5f;
        float inv4 = 0.25f / qw;
        float qx = (R21-R12)*inv4, qy=(R02-R20)*inv4, qz=(R10-R01)*inv4;
        float p0=v[6], p1=v[7], p2=v[8], p3=v[9];
        ar[0] = sis((c0 - cvr[0]) / (cvr[3]-cvr[0]));
        ar[1] = sis((c1 - cvr[1]) / (cvr[4]-cvr[1]));
        ar[2] = sis((c2 - cvr[2]) / (cvr[5]-cvr[2]));
        ar[3] = sis(v[3]); ar[4] = sis(v[4]); ar[5] = sis(v[5]);
        ar[6] = qw*p0 - qx*p1 - qy*p2 - qz*p3;
        ar[7] = qw*p1 + qx*p0 + qy*p3 - qz*p2;
        ar[8] = qw*p2 - qx*p3 + qy*p0 + qz*p1;
        ar[9] = qw*p3 + qx*p2 - qy*p1 + qz*p0;
        ar[10] = sis(v[10]);
        #pragma unroll
        for (int j = 0; j < 12; ++j) ar[11 + j] = v[11 + j];
    } else {
        #pragma unroll
        for (int j = 0; j < 23; ++j) ar[j] = 0.0f;
    }
    __syncthreads();

    {
        const float4* s = (const float4*)sB;
        float4* d = (float4*)(oP + base * 25);
        for (int k = t; k < 1600; k += 256) d[k] = s[k];
        const float4* s2 = (const float4*)sA;
        float4* d2 = (float4*)(oA + base * 23);
        for (int k = t; k < 1472; k += 256) d2[k] = s2[k];
    }
}

// ---------------------------------------------------------------------------
// Kernel 2: MFMA MLP. Dense over all rows, 64 rows/tile, 10 tiles/block.
// LDS images (bf16, 16B-granule XOR swizzle):
//  W2T[c=128][k=64], W3T[c=96][k=128], WiT[c=96][k=32(pad)],
//  H1[r=64][k=64], H2[r=64][c=128], AN[r=64][k=32(pad)]
// ---------------------------------------------------------------------------
#define W2T_OFF 0
#define W3T_OFF 16384
#define WIT_OFF 40960
#define H1_OFF  47104
#define H2_OFF  55296
#define AN_OFF  71680
#define B2_OFF  75776
#define BC_OFF  76288
#define M_OFF   76672
#define W1_OFF  76928
#define LDS_TOT 77696
#define NTILE   12500
#define GRID2   1250

__global__ __launch_bounds__(256) void k_mlp(
    const float* __restrict__ gp,
    const float* __restrict__ zbuf,
    const float* __restrict__ w2c,
    const float* __restrict__ ck,
    const float* __restrict__ W1, const float* __restrict__ b1,
    const float* __restrict__ W2, const float* __restrict__ b2,
    const float* __restrict__ W3, const float* __restrict__ b3,
    const float* __restrict__ Wi, const float* __restrict__ bi,
    const float* __restrict__ oA,
    const float* __restrict__ oM,
    float* __restrict__ oI)
{
    __shared__ __align__(16) char lds[LDS_TOT];
    float* sB2 = (float*)(lds + B2_OFF);
    float* sBC = (float*)(lds + BC_OFF);
    float* sM  = (float*)(lds + M_OFF);
    float* sW1 = (float*)(lds + W1_OFF);

    const int t = threadIdx.x;

    // ---- once per block: build bf16 weight images ----
    for (int idx = t; idx < 8192; idx += 256) {           // W2T: src-major (k,c)
        int k = idx >> 7, c = idx & 127;
        *(unsigned short*)(lds + W2T_OFF + c*128 + (((k>>3) ^ (c&7))<<4) + (k&7)*2)
            = f2bf(W2[idx]);
    }
    for (int idx = t; idx < 12288; idx += 256) {          // W3T: src-major (k,c)
        int k = idx / 96, c = idx - k*96;
        *(unsigned short*)(lds + W3T_OFF + c*256 + (((k>>3) ^ (c&15))<<4) + (k&7)*2)
            = f2bf(W3[idx]);
    }
    for (int idx = t; idx < 3072; idx += 256) {           // WiT: dest-major (c,k)
        int c = idx >> 5, k = idx & 31;
        float val = (k < 23) ? Wi[k*96 + c] : 0.0f;
        *(unsigned short*)(lds + WIT_OFF + c*64 + (((k>>3) ^ (c&3))<<4) + (k&7)*2)
            = f2bf(val);
    }
    if (t < 128) sB2[t] = b2[t];
    if (t < 96)  sBC[t] = b3[t] + bi[t];
    if (t < 192) sW1[t] = (t < 128) ? W1[t] : b1[t - 128];

    // hoisted uniforms
    float w00=w2c[0],w01=w2c[1],w02=w2c[2],w03=w2c[3];
    float w10=w2c[4],w11=w2c[5],w12=w2c[6],w13=w2c[7];
    float w20=w2c[8],w21=w2c[9],w22=w2c[10],w23=w2c[11];
    float k00=ck[0],k02=ck[2],k11=ck[4],k12=ck[5];

    const int r  = t & 63;       // staging row
    const int q  = t >> 6;       // staging quarter / wave id
    const int wv = t >> 6;
    const int ln = t & 63;
    const int la = ln & 15;
    const int lb = ln >> 4;

    __syncthreads();

    for (int tile = blockIdx.x; tile < NTILE; tile += GRID2) {
        const long R0 = (long)tile * 64;

        // ---- stage: mask, H1, anchor ----
        if (q == 0) sM[r] = oM[R0 + r];
        {
            const float* g = gp + (R0 + r) * 25;
            float x = g[0], y = g[1], zz = g[2];
            float c0 = w00*x + w01*y + w02*zz + w03;
            float c1 = w10*x + w11*y + w12*zz + w13;
            float c2 = w20*x + w21*y + w22*zz + w23;
            float czs = (fabsf(c2) < 1e-6f) ? 1e-6f : c2;
            float px = k00 * c0 / czs + k02;
            float py = k11 * c1 / czs + k12;
            int ix = (int)fminf(fmaxf(px, 0.f), 639.f);
            int iy = (int)fminf(fmaxf(py, 0.f), 479.f);
            float d0 = zbuf[iy * 640 + ix];
            float d1 = c2;
            U8 lo, hi;
            #pragma unroll
            for (int jj = 0; jj < 8; ++jj) {
                int j = q*16 + jj;
                lo.u[jj] = f2bf(fmaxf(fmaf(d0, sW1[j], fmaf(d1, sW1[64+j], sW1[128+j])), 0.f));
            }
            #pragma unroll
            for (int jj = 0; jj < 8; ++jj) {
                int j = q*16 + 8 + jj;
                hi.u[jj] = f2bf(fmaxf(fmaf(d0, sW1[j], fmaf(d1, sW1[64+j], sW1[128+j])), 0.f));
            }
            *(short8*)(lds + H1_OFF + r*128 + (((q*2    ) ^ (r&7))<<4)) = lo.v;
            *(short8*)(lds + H1_OFF + r*128 + (((q*2 + 1) ^ (r&7))<<4)) = hi.v;
        }
        {
            int r2 = t >> 2, g2 = t & 3;   // row, granule
            const float* ap = oA + (R0 + r2) * 23 + g2*8;
            U8 u;
            #pragma unroll
            for (int jj = 0; jj < 8; ++jj) {
                int k = g2*8 + jj;
                u.u[jj] = (k < 23) ? f2bf(ap[jj]) : (unsigned short)0;
            }
            *(short8*)(lds + AN_OFF + r2*64 + ((g2 ^ (r2&3))<<4)) = u.v;
        }
        __syncthreads();

        // ---- GEMM1: H2 = relu(H1 @ W2 + b2) ----
        {
            int row16 = wv*16 + la;
            short8 a0 = *(short8*)(lds + H1_OFF + row16*128 + (((lb    ) ^ (la&7))<<4));
            short8 a1 = *(short8*)(lds + H1_OFF + row16*128 + (((lb + 4) ^ (la&7))<<4));
            #pragma unroll
            for (int ct = 0; ct < 8; ++ct) {
                int c = ct*16 + la;
                short8 b0 = *(short8*)(lds + W2T_OFF + c*128 + (((lb    ) ^ (c&7))<<4));
                short8 b1v= *(short8*)(lds + W2T_OFF + c*128 + (((lb + 4) ^ (c&7))<<4));
                f32x4 acc = {0.f, 0.f, 0.f, 0.f};
                acc = __builtin_amdgcn_mfma_f32_16x16x32_bf16(a0, b0, acc, 0, 0, 0);
                acc = __builtin_amdgcn_mfma_f32_16x16x32_bf16(a1, b1v, acc, 0, 0, 0);
                float bb = sB2[c];
                #pragma unroll
                for (int j = 0; j < 4; ++j) {
                    int rr = wv*16 + lb*4 + j;
                    *(unsigned short*)(lds + H2_OFF + rr*256 + (((c>>3) ^ (rr&15))<<4) + (c&7)*2)
                        = f2bf(fmaxf(acc[j] + bb, 0.f));
                }
            }
        }
        __syncthreads();

        // ---- GEMM2: OUT = (H2@W3 + AN@Wi + bc) * mask ----
        {
            int row16 = wv*16 + la;
            short8 A[4];
            #pragma unroll
            for (int kt = 0; kt < 4; ++kt)
                A[kt] = *(short8*)(lds + H2_OFF + row16*256 + (((kt*4 + lb) ^ la)<<4));
            short8 aA = *(short8*)(lds + AN_OFF + row16*64 + ((lb ^ (la&3))<<4));
            float msk[4];
            #pragma unroll
            for (int j = 0; j < 4; ++j) msk[j] = sM[wv*16 + lb*4 + j];

            #pragma unroll
            for (int ct = 0; ct < 6; ++ct) {
                int c = ct*16 + la;
                f32x4 acc = {0.f, 0.f, 0.f, 0.f};
                #pragma unroll
                for (int kt = 0; kt < 4; ++kt) {
                    short8 B = *(short8*)(lds + W3T_OFF + c*256 + (((kt*4 + lb) ^ (c&15))<<4));
                    acc = __builtin_amdgcn_mfma_f32_16x16x32_bf16(A[kt], B, acc, 0, 0, 0);
                }
                short8 Bw = *(short8*)(lds + WIT_OFF + c*64 + ((lb ^ (c&3))<<4));
                acc = __builtin_amdgcn_mfma_f32_16x16x32_bf16(aA, Bw, acc, 0, 0, 0);
                float bb = sBC[c];
                #pragma unroll
                for (int j = 0; j < 4; ++j) {
                    int rr = wv*16 + lb*4 + j;
                    oI[(R0 + rr)*96 + c] = (msk[j] != 0.f) ? (acc[j] + bb) : 0.f;
                }
            }
        }
        __syncthreads();
    }
}

extern "C" void kernel_launch(void* const* d_in, const int* in_sizes, int n_in,
                              void* d_out, int out_size, void* d_ws, size_t ws_size,
                              hipStream_t stream)
{
    const float* gp  = (const float*)d_in[0];
    const float* zb  = (const float*)d_in[2];
    const float* w2c = (const float*)d_in[3];
    const float* ck  = (const float*)d_in[4];
    const float* vo  = (const float*)d_in[5];
    const float* ss  = (const float*)d_in[6];
    const float* cvr = (const float*)d_in[7];
    const float* Wi  = (const float*)d_in[8];
    const float* bi  = (const float*)d_in[9];
    const float* W1  = (const float*)d_in[10];
    const float* b1  = (const float*)d_in[11];
    const float* W2  = (const float*)d_in[12];
    const float* b2  = (const float*)d_in[13];
    const float* W3  = (const float*)d_in[14];
    const float* b3  = (const float*)d_in[15];

    float* out = (float*)d_out;
    const long N = NG;
    float* oA = out;               // (N,23)
    float* oT = out + 23L * N;     // (N,)
    float* oI = out + 24L * N;     // (N,96)
    float* oP = out + 120L * N;    // (N,25)
    float* oM = out + 145L * N;    // (N,)

    k_geom<<<NG / 256, 256, 0, stream>>>(gp, w2c, ck, vo, ss, cvr,
                                         oA, oT, oP, oM);
    k_mlp<<<GRID2, 256, 0, stream>>>(gp, zb, w2c, ck, W1, b1, W2, b2,
                                     W3, b3, Wi, bi, oA, oM, oI);
}

// Round 4
// 175.319 us; speedup vs baseline: 11.2193x; 1.4343x over previous
//
#include <hip/hip_runtime.h>
#include <math.h>

#define NG 800000        // = 3125*256 = 12500*64
#define NTILE 12500
#define GRID2 512

typedef __attribute__((ext_vector_type(8))) short short8;
typedef __attribute__((ext_vector_type(4))) float f32x4;

__device__ __forceinline__ float sis(float t) {
    t = fminf(fmaxf(t, 0.01f), 0.99f);
    return logf(t / (1.0f - t));
}
__device__ __forceinline__ unsigned short f2bf(float f) {
    unsigned int u = __float_as_uint(f);
    return (unsigned short)((u + 0x7FFFu + ((u >> 16) & 1u)) >> 16);
}
__device__ __forceinline__ unsigned int cvtpk(float a, float b) {
    unsigned int r;
    asm("v_cvt_pk_bf16_f32 %0, %1, %2" : "=v"(r) : "v"(a), "v"(b));
    return r;
}
__device__ __forceinline__ float bf2f(unsigned int u) {
    return __uint_as_float(u << 16);
}

// ---------------------------------------------------------------------------
// Kernel 1: geometry, masks, anchor, tag, pool copy, reuse mask + df pack.
// ---------------------------------------------------------------------------
__global__ __launch_bounds__(256) void k_geom(
    const float* __restrict__ gp,
    const float* __restrict__ zbuf,
    const float* __restrict__ w2c,
    const float* __restrict__ ck,
    const float* __restrict__ vo,
    const float* __restrict__ ss,
    const float* __restrict__ cvr,
    float* __restrict__ oA, float* __restrict__ oT,
    float* __restrict__ oP, float* __restrict__ oM,
    unsigned int* __restrict__ wdf, int usews)
{
    __shared__ __align__(16) float sB[256 * 25];
    __shared__ __align__(16) float sA[256 * 23];

    const long base = (long)blockIdx.x * 256;
    const int t = threadIdx.x;

    {
        const float4* src = (const float4*)(gp + base * 25);
        float4* dst = (float4*)sB;
        for (int k = t; k < 1600; k += 256) dst[k] = src[k];
    }
    __syncthreads();

    float v[25];
    #pragma unroll
    for (int j = 0; j < 25; ++j) v[j] = sB[t * 25 + j];

    float R00=w2c[0],R01=w2c[1],R02=w2c[2],T0=w2c[3];
    float R10=w2c[4],R11=w2c[5],R12=w2c[6],T1=w2c[7];
    float R20=w2c[8],R21=w2c[9],R22=w2c[10],T2=w2c[11];
    float x=v[0], y=v[1], zz=v[2];
    float c0 = R00*x + R01*y + R02*zz + T0;
    float c1 = R10*x + R11*y + R12*zz + T1;
    float c2 = R20*x + R21*y + R22*zz + T2;

    bool m1 = c2 > 1e-6f;
    float zc = m1 ? c2 : 1e-6f;
    float fpx = ck[0] * c0 / zc + ck[2];
    float fpy = ck[4] * c1 / zc + ck[5];
    bool m2 = (fpx >= 0.f) && (fpx < 640.f) && (fpy >= 0.f) && (fpy < 480.f);
    bool mall = m1 && m2;

    float n0=vo[0]+1e-3f, n1=vo[1]+1e-3f, n2=vo[2]+1e-3f;
    float f0=vo[0]+ss[0]-1e-3f, f1=vo[1]+ss[1]-1e-3f, f2=vo[2]+ss[2]-1e-3f;
    bool gpm = (x>n0)&&(x<f0)&&(y>n1)&&(y<f1)&&(zz>n2)&&(zz<f2);
    bool mdet = mall && gpm;

    sB[t * 25 + 24] = gpm ? 1.0f : v[24];

    float tag = (v[23] == 1.0f) ? 0.5f : 0.0f;
    if (!mdet) tag = 1.0f;

    bool gm = (c0>=cvr[0])&&(c0<=cvr[3])&&(c1>=cvr[1])&&(c1<=cvr[4])&&(c2>=cvr[2])&&(c2<=cvr[5]);
    bool reuse = gpm && gm;

    const long i = base + t;
    oM[i] = reuse ? 1.0f : 0.0f;
    oT[i] = reuse ? tag : 0.0f;

    // df = [z[iy,ix], depth_real] with cz_safe semantics
    if (usews) {
        float czs = (fabsf(c2) < 1e-6f) ? 1e-6f : c2;
        float px2 = ck[0]*c0/czs + ck[2];
        float py2 = ck[4]*c1/czs + ck[5];
        int ixq = (int)fminf(fmaxf(px2, 0.f), 639.f);
        int iyq = (int)fminf(fmaxf(py2, 0.f), 479.f);
        float dz = zbuf[iyq*640 + ixq];
        wdf[i] = (unsigned int)f2bf(dz) | ((unsigned int)f2bf(c2) << 16);
    }

    float* ar = &sA[t * 23];
    if (reuse) {
        float tr = R00 + R11 + R22;
        float qw = sqrtf(fmaxf(tr + 1.0f, 1e-8f)) * 0.5f;
        float inv4 = 0.25f / qw;
        float qx = (R21-R12)*inv4, qy=(R02-R20)*inv4, qz=(R10-R01)*inv4;
        float p0=v[6], p1=v[7], p2=v[8], p3=v[9];
        ar[0] = sis((c0 - cvr[0]) / (cvr[3]-cvr[0]));
        ar[1] = sis((c1 - cvr[1]) / (cvr[4]-cvr[1]));
        ar[2] = sis((c2 - cvr[2]) / (cvr[5]-cvr[2]));
        ar[3] = sis(v[3]); ar[4] = sis(v[4]); ar[5] = sis(v[5]);
        ar[6] = qw*p0 - qx*p1 - qy*p2 - qz*p3;
        ar[7] = qw*p1 + qx*p0 + qy*p3 - qz*p2;
        ar[8] = qw*p2 - qx*p3 + qy*p0 + qz*p1;
        ar[9] = qw*p3 + qx*p2 - qy*p1 + qz*p0;
        ar[10] = sis(v[10]);
        #pragma unroll
        for (int j = 0; j < 12; ++j) ar[11 + j] = v[11 + j];
    } else {
        #pragma unroll
        for (int j = 0; j < 23; ++j) ar[j] = 0.0f;
    }
    __syncthreads();

    {
        const float4* s = (const float4*)sB;
        float4* d = (float4*)(oP + base * 25);
        for (int k = t; k < 1600; k += 256) d[k] = s[k];
        const float4* s2 = (const float4*)sA;
        float4* d2 = (float4*)(oA + base * 23);
        for (int k = t; k < 1472; k += 256) d2[k] = s2[k];
    }
}

// ---------------------------------------------------------------------------
// Kernel 2: MFMA MLP, swapped operands (output-transposed D), reg-prefetch,
// raw barriers (no vmcnt drain). 64 rows/tile, persistent blocks.
// ---------------------------------------------------------------------------
#define W2T_OFF 0
#define W3T_OFF 16384
#define WIT_OFF 40960
#define H1_OFF  47104
#define H2_OFF  55296
#define AN_OFF  71680
#define B2_OFF  75776
#define BC_OFF  76288
#define M_OFF   76672
#define LDS_TOT 76928

__global__ __launch_bounds__(256, 2) void k_mlp(
    const float* __restrict__ gp,
    const float* __restrict__ zbuf,
    const float* __restrict__ w2c,
    const float* __restrict__ ck,
    const float* __restrict__ W1, const float* __restrict__ b1,
    const float* __restrict__ W2, const float* __restrict__ b2,
    const float* __restrict__ W3, const float* __restrict__ b3,
    const float* __restrict__ Wi, const float* __restrict__ bi,
    const float* __restrict__ oA,
    const float* __restrict__ oM,
    float* __restrict__ oI,
    const unsigned int* __restrict__ wdf, int usews)
{
    __shared__ __align__(16) char lds[LDS_TOT];
    float* sB2 = (float*)(lds + B2_OFF);
    float* sBC = (float*)(lds + BC_OFF);
    float* sM  = (float*)(lds + M_OFF);

    const int t  = threadIdx.x;
    const int wv = t >> 6;
    const int l  = t & 63;
    const int la = l & 15;
    const int lb = l >> 4;
    const int r2 = t >> 2;                       // AN staging row
    const int gg = ((t & 3) + (r2 >> 2)) & 3;    // AN staging granule (rotated)
    const int q2 = (wv + (l >> 3)) & 3;          // H1 col-block (rotated)

    // ---- build weight images (once per block) ----
    for (int idx = t; idx < 8192; idx += 256) {
        int k = idx >> 7, c = idx & 127;
        *(unsigned short*)(lds + W2T_OFF + c*128 + (((k>>3) ^ (c&7))<<4) + (k&7)*2)
            = f2bf(W2[idx]);
    }
    for (int idx = t; idx < 12288; idx += 256) {
        int k = idx / 96, c = idx - k*96;
        *(unsigned short*)(lds + W3T_OFF + c*256 + (((k>>3) ^ (c&15))<<4) + (k&7)*2)
            = f2bf(W3[idx]);
    }
    for (int idx = t; idx < 3072; idx += 256) {
        int c = idx >> 5, k = idx & 31;
        float val = (k < 23) ? Wi[k*96 + c] : 0.0f;
        *(unsigned short*)(lds + WIT_OFF + c*64 + (((k>>3) ^ (c&3))<<4) + (k&7)*2)
            = f2bf(val);
    }
    if (t < 128) sB2[t] = b2[t];
    if (t < 96)  sBC[t] = b3[t] + bi[t];

    // per-thread W1/b1 columns (q2 block) in registers
    float4 w1a[4], w1b[4], b1r[4];
    #pragma unroll
    for (int gi = 0; gi < 4; ++gi) {
        w1a[gi] = *(const float4*)&W1[q2*16 + gi*4];
        w1b[gi] = *(const float4*)&W1[64 + q2*16 + gi*4];
        b1r[gi] = *(const float4*)&b1[q2*16 + gi*4];
    }

    // fallback uniforms
    float w00=w2c[0],w01=w2c[1],w02=w2c[2],w03=w2c[3];
    float w10=w2c[4],w11=w2c[5],w12=w2c[6],w13=w2c[7];
    float w20=w2c[8],w21=w2c[9],w22=w2c[10],w23v=w2c[11];
    float k00=ck[0],k02=ck[2],k11=ck[4],k12=ck[5];

    __syncthreads();   // weights visible (once; prefetch issued after)

    // ---- initial prefetch ----
    unsigned int df_pf = 0;
    float xp=0.f, yp=0.f, zp=0.f;
    float an_pf[8];
    float mk_pf = 0.f;
    {
        const long Rn = (long)blockIdx.x * 64;
        if (usews) df_pf = wdf[Rn + l];
        else { const float* g = gp + (Rn + l)*25; xp = g[0]; yp = g[1]; zp = g[2]; }
        const float* apn = oA + (Rn + r2)*23 + gg*8;
        #pragma unroll
        for (int jj = 0; jj < 8; ++jj) {
            int k = gg*8 + jj;
            an_pf[jj] = (k < 23) ? apn[jj] : 0.0f;
        }
        if (wv == 0) mk_pf = oM[Rn + l];
    }

    const int rB = wv*16 + la;

    for (int tile = blockIdx.x; tile < NTILE; tile += GRID2) {
        const long R0 = (long)tile * 64;

        // ---- Phase S: publish current tile to LDS ----
        if (wv == 0) sM[l] = mk_pf;
        float d0, d1;
        if (usews) { d0 = bf2f(df_pf & 0xFFFFu); d1 = bf2f(df_pf >> 16); }
        else {
            float c0 = w00*xp + w01*yp + w02*zp + w03;
            float c1 = w10*xp + w11*yp + w12*zp + w13;
            float c2 = w20*xp + w21*yp + w22*zp + w23v;
            float czs = (fabsf(c2) < 1e-6f) ? 1e-6f : c2;
            float px = k00*c0/czs + k02;
            float py = k11*c1/czs + k12;
            int ix = (int)fminf(fmaxf(px, 0.f), 639.f);
            int iy = (int)fminf(fmaxf(py, 0.f), 479.f);
            d0 = zbuf[iy*640 + ix];
            d1 = c2;
        }
        {
            float h[16];
            #pragma unroll
            for (int gi = 0; gi < 4; ++gi) {
                h[gi*4+0] = fmaxf(fmaf(d0, w1a[gi].x, fmaf(d1, w1b[gi].x, b1r[gi].x)), 0.f);
                h[gi*4+1] = fmaxf(fmaf(d0, w1a[gi].y, fmaf(d1, w1b[gi].y, b1r[gi].y)), 0.f);
                h[gi*4+2] = fmaxf(fmaf(d0, w1a[gi].z, fmaf(d1, w1b[gi].z, b1r[gi].z)), 0.f);
                h[gi*4+3] = fmaxf(fmaf(d0, w1a[gi].w, fmaf(d1, w1b[gi].w, b1r[gi].w)), 0.f);
            }
            uint4 pa, pb;
            pa.x = cvtpk(h[0],h[1]);  pa.y = cvtpk(h[2],h[3]);
            pa.z = cvtpk(h[4],h[5]);  pa.w = cvtpk(h[6],h[7]);
            pb.x = cvtpk(h[8],h[9]);  pb.y = cvtpk(h[10],h[11]);
            pb.z = cvtpk(h[12],h[13]);pb.w = cvtpk(h[14],h[15]);
            int pg0 = (2*q2)     ^ (l & 7);
            int pg1 = (2*q2 + 1) ^ (l & 7);
            *(uint4*)(lds + H1_OFF + l*128 + (pg0<<4)) = pa;
            *(uint4*)(lds + H1_OFF + l*128 + (pg1<<4)) = pb;
        }
        {
            uint4 anp;
            anp.x = cvtpk(an_pf[0], an_pf[1]);
            anp.y = cvtpk(an_pf[2], an_pf[3]);
            anp.z = cvtpk(an_pf[4], an_pf[5]);
            anp.w = cvtpk(an_pf[6], an_pf[7]);
            int pga = gg ^ (r2 & 3);
            *(uint4*)(lds + AN_OFF + r2*64 + (pga<<4)) = anp;
        }
        asm volatile("s_waitcnt lgkmcnt(0)" ::: "memory");
        __builtin_amdgcn_s_barrier();

        // ---- Phase P: prefetch next tile into registers ----
        {
            int tn = tile + GRID2; if (tn >= NTILE) tn = tile;
            const long Rn = (long)tn * 64;
            if (usews) df_pf = wdf[Rn + l];
            else { const float* g = gp + (Rn + l)*25; xp = g[0]; yp = g[1]; zp = g[2]; }
            const float* apn = oA + (Rn + r2)*23 + gg*8;
            #pragma unroll
            for (int jj = 0; jj < 8; ++jj) {
                int k = gg*8 + jj;
                an_pf[jj] = (k < 23) ? apn[jj] : 0.0f;
            }
            if (wv == 0) mk_pf = oM[Rn + l];
        }

        // ---- GEMM1 (swapped): lane holds H2[rB][ct*16+lb*4+j] ----
        {
            short8 hb0 = *(short8*)(lds + H1_OFF + rB*128 + (((lb  ) ^ (rB&7))<<4));
            short8 hb1 = *(short8*)(lds + H1_OFF + rB*128 + (((lb+4) ^ (rB&7))<<4));
            #pragma unroll
            for (int ct = 0; ct < 8; ++ct) {
                const int c = ct*16 + la;
                short8 a0 = *(short8*)(lds + W2T_OFF + c*128 + (((lb  ) ^ (c&7))<<4));
                short8 a1 = *(short8*)(lds + W2T_OFF + c*128 + (((lb+4) ^ (c&7))<<4));
                f32x4 acc = {0.f, 0.f, 0.f, 0.f};
                acc = __builtin_amdgcn_mfma_f32_16x16x32_bf16(a0, hb0, acc, 0, 0, 0);
                acc = __builtin_amdgcn_mfma_f32_16x16x32_bf16(a1, hb1, acc, 0, 0, 0);
                float4 bb = *(float4*)&sB2[ct*16 + lb*4];
                float e0 = fmaxf(acc[0] + bb.x, 0.f);
                float e1 = fmaxf(acc[1] + bb.y, 0.f);
                float e2 = fmaxf(acc[2] + bb.z, 0.f);
                float e3 = fmaxf(acc[3] + bb.w, 0.f);
                uint2 pk; pk.x = cvtpk(e0, e1); pk.y = cvtpk(e2, e3);
                const int g = ct*2 + (lb>>1);
                *(uint2*)(lds + H2_OFF + rB*256 + ((g ^ (rB&15))<<4) + (lb&1)*8) = pk;
            }
        }
        asm volatile("s_waitcnt lgkmcnt(0)" ::: "memory");
        __builtin_amdgcn_s_barrier();

        // ---- GEMM2 (swapped): lane stores float4 of row rB ----
        {
            short8 B0 = *(short8*)(lds + H2_OFF + rB*256 + ((( 0 + lb) ^ (rB&15))<<4));
            short8 B1 = *(short8*)(lds + H2_OFF + rB*256 + ((( 4 + lb) ^ (rB&15))<<4));
            short8 B2v= *(short8*)(lds + H2_OFF + rB*256 + ((( 8 + lb) ^ (rB&15))<<4));
            short8 B3 = *(short8*)(lds + H2_OFF + rB*256 + (((12 + lb) ^ (rB&15))<<4));
            short8 bA = *(short8*)(lds + AN_OFF + rB*64 + ((lb ^ (rB&3))<<4));
            float mk2 = sM[rB];
            float* orow = oI + (R0 + rB) * 96;
            #pragma unroll
            for (int ct = 0; ct < 6; ++ct) {
                const int c = ct*16 + la;
                f32x4 acc = {0.f, 0.f, 0.f, 0.f};
                short8 A0 = *(short8*)(lds + W3T_OFF + c*256 + ((( 0 + lb) ^ (c&15))<<4));
                short8 A1 = *(short8*)(lds + W3T_OFF + c*256 + ((( 4 + lb) ^ (c&15))<<4));
                short8 A2 = *(short8*)(lds + W3T_OFF + c*256 + ((( 8 + lb) ^ (c&15))<<4));
                short8 A3 = *(short8*)(lds + W3T_OFF + c*256 + (((12 + lb) ^ (c&15))<<4));
                acc = __builtin_amdgcn_mfma_f32_16x16x32_bf16(A0, B0, acc, 0, 0, 0);
                acc = __builtin_amdgcn_mfma_f32_16x16x32_bf16(A1, B1, acc, 0, 0, 0);
                acc = __builtin_amdgcn_mfma_f32_16x16x32_bf16(A2, B2v, acc, 0, 0, 0);
                acc = __builtin_amdgcn_mfma_f32_16x16x32_bf16(A3, B3, acc, 0, 0, 0);
                short8 Aw = *(short8*)(lds + WIT_OFF + c*64 + ((lb ^ (c&3))<<4));
                acc = __builtin_amdgcn_mfma_f32_16x16x32_bf16(Aw, bA, acc, 0, 0, 0);
                float4 bb = *(float4*)&sBC[ct*16 + lb*4];
                float4 o;
                o.x = (mk2 != 0.f) ? acc[0] + bb.x : 0.f;
                o.y = (mk2 != 0.f) ? acc[1] + bb.y : 0.f;
                o.z = (mk2 != 0.f) ? acc[2] + bb.z : 0.f;
                o.w = (mk2 != 0.f) ? acc[3] + bb.w : 0.f;
                *(float4*)(orow + ct*16 + lb*4) = o;
            }
        }
        asm volatile("s_waitcnt lgkmcnt(0)" ::: "memory");
        __builtin_amdgcn_s_barrier();
    }
}

extern "C" void kernel_launch(void* const* d_in, const int* in_sizes, int n_in,
                              void* d_out, int out_size, void* d_ws, size_t ws_size,
                              hipStream_t stream)
{
    const float* gp  = (const float*)d_in[0];
    const float* zb  = (const float*)d_in[2];
    const float* w2c = (const float*)d_in[3];
    const float* ck  = (const float*)d_in[4];
    const float* vo  = (const float*)d_in[5];
    const float* ss  = (const float*)d_in[6];
    const float* cvr = (const float*)d_in[7];
    const float* Wi  = (const float*)d_in[8];
    const float* bi  = (const float*)d_in[9];
    const float* W1  = (const float*)d_in[10];
    const float* b1  = (const float*)d_in[11];
    const float* W2  = (const float*)d_in[12];
    const float* b2  = (const float*)d_in[13];
    const float* W3  = (const float*)d_in[14];
    const float* b3  = (const float*)d_in[15];

    float* out = (float*)d_out;
    const long N = NG;
    float* oA = out;               // (N,23)
    float* oT = out + 23L * N;     // (N,)
    float* oI = out + 24L * N;     // (N,96)
    float* oP = out + 120L * N;    // (N,25)
    float* oM = out + 145L * N;    // (N,)

    int usews = (ws_size >= (size_t)(4 * (size_t)NG)) ? 1 : 0;
    unsigned int* wdf = (unsigned int*)d_ws;

    k_geom<<<NG / 256, 256, 0, stream>>>(gp, zb, w2c, ck, vo, ss, cvr,
                                         oA, oT, oP, oM, wdf, usews);
    k_mlp<<<GRID2, 256, 0, stream>>>(gp, zb, w2c, ck, W1, b1, W2, b2,
                                     W3, b3, Wi, bi, oA, oM, oI, wdf, usews);
}